// Round 1
// 903.482 us; speedup vs baseline: 1.0313x; 1.0313x over previous
//
#include <hip/hip_runtime.h>
#include <hip/hip_bf16.h>
#include <stdint.h>

typedef __attribute__((ext_vector_type(8))) short short8;
typedef __attribute__((ext_vector_type(4))) float floatx4;
typedef unsigned short u16;
typedef unsigned int u32;
typedef unsigned long long u64;

static __device__ __forceinline__ u16 f2bf(float f) {
  union { float f; u32 u; } v; v.f = f;
  return (u16)((v.u + 0x7fffu + ((v.u >> 16) & 1u)) >> 16);
}
static __device__ __forceinline__ float bf2f(u16 h) {
  union { u32 u; float f; } v; v.u = ((u32)h) << 16; return v.f;
}
static __device__ __forceinline__ u64 pack4(float a, float b, float c, float d) {
  return (u64)f2bf(a) | ((u64)f2bf(b) << 16) | ((u64)f2bf(c) << 32) | ((u64)f2bf(d) << 48);
}

// ---------------- conversions ----------------
__global__ __launch_bounds__(256) void k_cvt(const float* __restrict__ src, u16* __restrict__ dst, int nquad) {
  int i = blockIdx.x * 256 + threadIdx.x;
  int stride = gridDim.x * 256;
  for (; i < nquad; i += stride) {
    float4 v = ((const float4*)src)[i];
    ((u64*)dst)[i] = pack4(v.x, v.y, v.z, v.w);
  }
}

// conv weights (K,1,ws,1024) -> Wc[4608][1024] bf16, rows = [ws2: j*512+k | ws3 | ws4]
__global__ __launch_bounds__(256) void k_cvt_wc(const float* __restrict__ w2, const float* __restrict__ w3,
                                                const float* __restrict__ w4, u16* __restrict__ wc) {
  int i = blockIdx.x * 256 + threadIdx.x;
  int stride = gridDim.x * 256;
  const int nquad = 4608 * 1024 / 4;
  for (; i < nquad; i += stride) {
    int e = i << 2;
    int row = e >> 10, col = e & 1023;
    const float* src;
    if (row < 1024)      { int j = row >> 9, k = row & 511;               src = w2 + (k * 2 + j) * 1024; }
    else if (row < 2560) { int m = row - 1024; int j = m >> 9, k = m & 511; src = w3 + (k * 3 + j) * 1024; }
    else                 { int m = row - 2560; int j = m >> 9, k = m & 511; src = w4 + (k * 4 + j) * 1024; }
    float4 v = *(const float4*)(src + col);
    ((u64*)wc)[i] = pack4(v.x, v.y, v.z, v.w);
  }
}

__global__ __launch_bounds__(256) void k_prep(const float* __restrict__ bih_f, const float* __restrict__ bih_b,
    const float* __restrict__ fcb, const float* __restrict__ gam, const float* __restrict__ bet,
    const float* __restrict__ mu, const float* __restrict__ var,
    float* __restrict__ bihcat, float* __restrict__ bns, float* __restrict__ bnt) {
  int i = blockIdx.x * 256 + threadIdx.x;
  if (i < 3072) bihcat[i] = (i < 1536) ? bih_f[i] : bih_b[i - 1536];
  if (i < 2048) {
    float s = gam[i] * rsqrtf(var[i] + 1e-5f);
    bns[i] = s;
    bnt[i] = s * (fcb[i] - mu[i]) + bet[i];
  }
}

// ---------------- generic bf16 MFMA GEMM: C[M,N] = A[M,K] * B[N,K]^T
// kn = number of 32-wide k-tiles this block processes; k-tile base = blockIdx.z * kn.
// f32 partial output goes to C + blockIdx.z*M*N (split-K); bf16 path via C16.
static __device__ __forceinline__ void gload_lds16(const u16* g, u16* l) {
  __builtin_amdgcn_global_load_lds((const __attribute__((address_space(1))) u32*)(const void*)g,
                                   (__attribute__((address_space(3))) u32*)(void*)l, 16, 0, 0);
}

__global__ __launch_bounds__(256) void gemm_bt(
    const u16* __restrict__ A, const u16* __restrict__ Bm,
    float* __restrict__ C, u16* __restrict__ C16, int M, int N, int K, int kn,
    const float* __restrict__ scale, const float* __restrict__ shift)
{
  __shared__ u16 As[128 * 32];
  __shared__ u16 Bs[128 * 32];
  int tid = threadIdx.x, lane = tid & 63, wid = tid >> 6;
  int m0 = blockIdx.y * 128, n0 = blockIdx.x * 128;
  int kt0 = blockIdx.z * kn;
  int wr = wid >> 1, wc = wid & 1;
  int r16 = lane & 15, kq = lane >> 4;
  const floatx4 z4 = {0.f, 0.f, 0.f, 0.f};
  floatx4 acc[4][4];
#pragma unroll
  for (int i = 0; i < 4; ++i)
#pragma unroll
    for (int j = 0; j < 4; ++j) acc[i][j] = z4;
  for (int kt = kt0; kt < kt0 + kn; ++kt) {
    __syncthreads();
#pragma unroll
    for (int inst = 0; inst < 2; ++inst) {
      int g = inst * 256 + tid;
      int row = g >> 2, cb = g & 3;
      const u16* ga = A + (long)(m0 + row) * K + kt * 32 + cb * 8;
      const u16* gb = Bm + (long)(n0 + row) * K + kt * 32 + cb * 8;
      gload_lds16(ga, &As[(inst * 256 + wid * 64) * 8]);
      gload_lds16(gb, &Bs[(inst * 256 + wid * 64) * 8]);
    }
    __syncthreads();
    short8 af[4], bf[4];
#pragma unroll
    for (int mt = 0; mt < 4; ++mt) af[mt] = *(const short8*)&As[(wr * 64 + mt * 16 + r16) * 32 + kq * 8];
#pragma unroll
    for (int nt = 0; nt < 4; ++nt) bf[nt] = *(const short8*)&Bs[(wc * 64 + nt * 16 + r16) * 32 + kq * 8];
#pragma unroll
    for (int mt = 0; mt < 4; ++mt)
#pragma unroll
      for (int nt = 0; nt < 4; ++nt)
        acc[mt][nt] = __builtin_amdgcn_mfma_f32_16x16x32_bf16(af[mt], bf[nt], acc[mt][nt], 0, 0, 0);
  }
  float* Cp = C + (long)blockIdx.z * M * N;
#pragma unroll
  for (int nt = 0; nt < 4; ++nt) {
    int col = n0 + wc * 64 + nt * 16 + r16;
    float sc = scale ? scale[col] : 1.f;
    float sh = shift ? shift[col] : 0.f;
#pragma unroll
    for (int mt = 0; mt < 4; ++mt)
#pragma unroll
      for (int q = 0; q < 4; ++q) {
        int row = m0 + wr * 64 + mt * 16 + kq * 4 + q;
        float v = acc[mt][nt][q] * sc + sh;
        if (C16) C16[(long)row * N + col] = f2bf(v);
        else     Cp[(long)row * N + col] = v;
      }
  }
}

// ---------------- GRU recurrence ----------------
// 128 blocks x 512 threads = dir(2) x b-tile(8 of 16 batches) x i-slice(8 of 64 i).
// Whh frags in registers. Group = 8 i-slice blocks sharing (dir, bt).
// NO __syncthreads in the loop: one raw s_barrier+lgkmcnt for the LDS partial
// exchange (ks1 -> ks0), parity-double-buffered. Per-WAVE flags: each ks0 wave
// drains only its own stores (asm vmcnt(0)) then publishes.
// POLL DISCIPLINE (this round): only wave 0 of each block polls the group's 32
// flags, with s_sleep backoff; other waves wait at a raw s_barrier. All-wave
// unthrottled agent polling floods the flag cache lines with coherent reads and
// queues the critical publish store behind them (~17k cy/step observed vs ~3k
// modeled). Raw s_barrier (not __syncthreads) so the previous step's hs store
// drain stays off the critical path; LDS parity double-buffer makes the extra
// barrier hazard-free.
__global__ __launch_bounds__(512) void gru_rec(
    const float* __restrict__ xg,     // [8192][3072]
    const u16* __restrict__ whhb,     // [2][1536][512] bf16
    const float* __restrict__ bhh_f, const float* __restrict__ bhh_b,
    u16* __restrict__ hbuf,           // [2 parity][2 dir][128][512] bf16 (zeroed each launch)
    float* __restrict__ hs,           // [128][64][1024] fp32
    int* __restrict__ flg)            // 512 flags x 16 ints (64B lines), zeroed each launch
{
  __shared__ float part[2][4][3][256];
  int tid = threadIdx.x, lane = tid & 63, wid = tid >> 6;
  int bid = blockIdx.x;
  int dir = bid >> 6, rem = bid & 63, bt = rem >> 3, is = rem & 7;
  int ih = wid & 3, ks = wid >> 2;
  int gbase = (dir * 8 + bt) * 32;
  int r16 = lane & 15, kq = lane >> 4;
  int iglob = is * 64 + ih * 16 + r16;       // i index of this lane's weight rows
  int i0 = is * 64 + ih * 16 + kq * 4;       // i base of this lane's 4 outputs
  int batch = bt * 16 + r16;                 // this lane's output batch (global)
  int pollidx = (gbase + (lane & 31)) * 16;
  int pubidx = (gbase + is * 4 + ih) * 16;
  const float* bhh = dir ? bhh_b : bhh_f;
  const floatx4 z4 = {0.f, 0.f, 0.f, 0.f};

  short8 wfrag[3][8];
#pragma unroll
  for (int g = 0; g < 3; ++g) {
    const u16* wrow = whhb + (long)(dir * 1536 + g * 512 + iglob) * 512;
#pragma unroll
    for (int kk = 0; kk < 8; ++kk)
      wfrag[g][kk] = *(const short8*)&wrow[(ks * 8 + kk) * 32 + kq * 8];
  }
  float4 bh4[3];
#pragma unroll
  for (int g = 0; g < 3; ++g) bh4[g] = *(const float4*)&bhh[g * 512 + i0];
  float4 hprev = {0.f, 0.f, 0.f, 0.f};

  float4 px[3];
  if (ks == 0) {
    int ts0 = dir ? 63 : 0;
    long xb = (long)(batch * 64 + ts0) * 3072 + dir * 1536 + i0;
#pragma unroll
    for (int g = 0; g < 3; ++g) px[g] = *(const float4*)&xg[xb + g * 512];
  }

  for (int t = 0; t < 64; ++t) {
    // 1. wait for all group blocks to have finished step t-1.
    //    Single poller wave per block + sleep backoff; raw barrier releases the rest.
    if (t > 0) {
      if (wid == 0) {
        while (true) {
          int v = __hip_atomic_load(&flg[pollidx], __ATOMIC_RELAXED, __HIP_MEMORY_SCOPE_AGENT);
          if (__all(v >= t)) break;
          __builtin_amdgcn_s_sleep(1);
        }
      }
      asm volatile("s_barrier" ::: "memory");
    }
    int par = t & 1;
    // 2. issue next-step xg prefetch first (longest latency, consumed latest)
    float4 pxn[3];
    if (ks == 0 && t < 63) {
      int ts1 = dir ? (62 - t) : (t + 1);
      long xb = (long)(batch * 64 + ts1) * 3072 + dir * 1536 + i0;
#pragma unroll
      for (int g = 0; g < 3; ++g) pxn[g] = *(const float4*)&xg[xb + g * 512];
    }
    // 3. h loads (L3 coherence point)
    const u16* hsrc = hbuf + (long)((par * 2 + dir) * 128 + bt * 16) * 512;
    union { u64 q[2]; short8 v; } hu[8];
#pragma unroll
    for (int kk = 0; kk < 8; ++kk) {
      const u64* hp = (const u64*)&hsrc[r16 * 512 + (ks * 8 + kk) * 32 + kq * 8];
      hu[kk].q[0] = __hip_atomic_load(hp,     __ATOMIC_RELAXED, __HIP_MEMORY_SCOPE_AGENT);
      hu[kk].q[1] = __hip_atomic_load(hp + 1, __ATOMIC_RELAXED, __HIP_MEMORY_SCOPE_AGENT);
    }
    floatx4 acc[3];
#pragma unroll
    for (int g = 0; g < 3; ++g) acc[g] = z4;
#pragma unroll
    for (int kk = 0; kk < 8; ++kk)
#pragma unroll
      for (int g = 0; g < 3; ++g)
        acc[g] = __builtin_amdgcn_mfma_f32_16x16x32_bf16(wfrag[g][kk], hu[kk].v, acc[g], 0, 0, 0);
    if (ks == 1) {
#pragma unroll
      for (int g = 0; g < 3; ++g) *(floatx4*)&part[par][ih][g][lane * 4] = acc[g];
    }
    // LDS-only barrier: order ks1 ds_writes before ks0 ds_reads; no vmcnt drain.
    asm volatile("s_waitcnt lgkmcnt(0)\n\ts_barrier" ::: "memory");
    if (ks == 0) {
      int tsrc = dir ? (63 - t) : t;
#pragma unroll
      for (int g = 0; g < 3; ++g) acc[g] += *(const floatx4*)&part[par][ih][g][lane * 4];
      float4 hn4;
#pragma unroll
      for (int q = 0; q < 4; ++q) {
        float rr = acc[0][q] + ((const float*)&bh4[0])[q] + ((const float*)&px[0])[q];
        float zz = acc[1][q] + ((const float*)&bh4[1])[q] + ((const float*)&px[1])[q];
        float r = 1.f / (1.f + __expf(-rr));
        float z = 1.f / (1.f + __expf(-zz));
        float n = tanhf(((const float*)&px[2])[q] + r * (acc[2][q] + ((const float*)&bh4[2])[q]));
        ((float*)&hn4)[q] = (1.f - z) * n + z * ((const float*)&hprev)[q];
      }
      hprev = hn4;
      u16* hdst = hbuf + (long)(((par ^ 1) * 2 + dir) * 128 + bt * 16) * 512;
      __hip_atomic_store((u64*)&hdst[r16 * 512 + i0], pack4(hn4.x, hn4.y, hn4.z, hn4.w),
                         __ATOMIC_RELAXED, __HIP_MEMORY_SCOPE_AGENT);
      if (t < 63) {
        // drain own stores (h store; xg prefetch is ~1500cy old by now), then publish
        asm volatile("s_waitcnt vmcnt(0)" ::: "memory");
        if (lane == 0)
          __hip_atomic_store(&flg[pubidx], t + 1, __ATOMIC_RELAXED, __HIP_MEMORY_SCOPE_AGENT);
      }
      // hs store off the critical path (drains at next step's vmcnt(0))
      *(float4*)&hs[(long)(batch * 64 + tsrc) * 1024 + dir * 512 + i0] = hn4;
      px[0] = pxn[0]; px[1] = pxn[1]; px[2] = pxn[2];
    }
  }
}

// ---------------- mask + mean-pool + feature assembly ----------------
__global__ __launch_bounds__(256) void k_mask_pool(
    const float* __restrict__ hs, const int* __restrict__ lengths,
    const float* __restrict__ vo, const float* __restrict__ mo,
    u16* __restrict__ maskedb, u16* __restrict__ feat)
{
  int b = blockIdx.x, tid = threadIdx.x;
  int len = lengths[b];
  float inv = 1.0f / (float)len;
  int c0 = tid * 4;
  float s0 = 0.f, s1 = 0.f, s2 = 0.f, s3 = 0.f;
  for (int t = 0; t < 64; ++t) {
    float4 v = *(const float4*)&hs[(long)(b * 64 + t) * 1024 + c0];
    u64 pk = 0ull;
    if (t < len) {
      s0 += v.x; s1 += v.y; s2 += v.z; s3 += v.w;
      pk = pack4(v.x, v.y, v.z, v.w);
    }
    *(u64*)&maskedb[(long)(b * 64 + t) * 1024 + c0] = pk;
  }
  u16* fb = feat + (long)b * 5632;
  *(u64*)&fb[c0] = pack4(s0 * inv, s1 * inv, s2 * inv, s3 * inv);
  {
    int c = tid * 8;
    float4 a = *(const float4*)&vo[(long)b * 2048 + c];
    float4 d = *(const float4*)&vo[(long)b * 2048 + c + 4];
    *(u64*)&fb[2560 + c] = pack4(a.x, a.y, a.z, a.w);
    *(u64*)&fb[2560 + c + 4] = pack4(d.x, d.y, d.z, d.w);
  }
  {
    float4 a = *(const float4*)&mo[(long)b * 1024 + c0];
    *(u64*)&fb[4608 + c0] = pack4(a.x, a.y, a.z, a.w);
  }
}

// ---------------- conv shift-add + relu + max over positions (z is bf16) ----------------
__global__ __launch_bounds__(512) void k_conv_finish(
    const u16* __restrict__ z, const float* __restrict__ cb2,
    const float* __restrict__ cb3, const float* __restrict__ cb4,
    u16* __restrict__ feat)
{
  int b = blockIdx.x, wsi = blockIdx.y, k = threadIdx.x;
  int ws = wsi + 2;
  int base = (wsi == 0) ? 0 : (wsi == 1 ? 1024 : 2560);
  const float* cb = (wsi == 0) ? cb2 : (wsi == 1 ? cb3 : cb4);
  float bias = cb[k];
  float m = 0.f;  // relu floor
  for (int p = 0; p < 64 + ws - 1; ++p) {
    float acc = bias;
    for (int j = 0; j < ws; ++j) {
      int t = p - (ws - 1) + j;
      if (t >= 0 && t < 64)
        acc += bf2f(z[(long)(b * 64 + t) * 4608 + base + j * 512 + k]);
    }
    m = fmaxf(m, acc);
  }
  feat[(long)b * 5632 + 1024 + wsi * 512 + k] = f2bf(m);
}

// ---------------- split-K reduce + BN + row L2 normalize ----------------
__global__ __launch_bounds__(256) void k_l2norm(const float* __restrict__ p,
    const float* __restrict__ bns, const float* __restrict__ bnt, float* __restrict__ out)
{
  __shared__ float red[4];
  int b = blockIdx.x, tid = threadIdx.x;
  float v[8]; float s = 0.f;
#pragma unroll
  for (int j = 0; j < 8; ++j) {
    int i = j * 256 + tid;
    long o = (long)b * 2048 + i;
    float a = p[o] + p[o + 262144] + p[o + 524288] + p[o + 786432];
    a = a * bns[i] + bnt[i];
    v[j] = a; s += a * a;
  }
#pragma unroll
  for (int o = 32; o > 0; o >>= 1) s += __shfl_down(s, o);
  if ((tid & 63) == 0) red[tid >> 6] = s;
  __syncthreads();
  float rn = rsqrtf(red[0] + red[1] + red[2] + red[3]);
#pragma unroll
  for (int j = 0; j < 8; ++j)
    out[(long)b * 2048 + j * 256 + tid] = v[j] * rn;
}

// ---------------- launch ----------------
extern "C" void kernel_launch(void* const* d_in, const int* in_sizes, int n_in,
                              void* d_out, int out_size, void* d_ws, size_t ws_size,
                              hipStream_t stream)
{
  (void)in_sizes; (void)n_in; (void)out_size; (void)ws_size;
  const float* videos       = (const float*)d_in[0];
  const float* motions      = (const float*)d_in[1];
  const float* videos_origin= (const float*)d_in[2];
  const int*   lengths      = (const int*)d_in[3];
  const float* Wih_f = (const float*)d_in[4];
  const float* Whh_f = (const float*)d_in[5];
  const float* bih_f = (const float*)d_in[6];
  const float* bhh_f = (const float*)d_in[7];
  const float* Wih_b = (const float*)d_in[8];
  const float* Whh_b = (const float*)d_in[9];
  const float* bih_b = (const float*)d_in[10];
  const float* bhh_b = (const float*)d_in[11];
  const float* fc_w  = (const float*)d_in[12];
  const float* fc_b  = (const float*)d_in[13];
  const float* bn_gamma = (const float*)d_in[14];
  const float* bn_beta  = (const float*)d_in[15];
  const float* bn_mean  = (const float*)d_in[16];
  const float* bn_var   = (const float*)d_in[17];
  const float* conv_w2 = (const float*)d_in[18];
  const float* conv_b2 = (const float*)d_in[19];
  const float* conv_w3 = (const float*)d_in[20];
  const float* conv_b3 = (const float*)d_in[21];
  const float* conv_w4 = (const float*)d_in[22];
  const float* conv_b4 = (const float*)d_in[23];
  float* out = (float*)d_out;
  char* w = (char*)d_ws;

  // workspace layout (bytes). z (bf16) overlays XG; FC split-K partials overlay MASKB.
  const size_t XG    = 0;              // 8192x3072 f32 = 100,663,296
  const size_t HS    = 100663296;      // 128x64x1024 f32 = 33,554,432
  const size_t VID   = 134217728;      // 8192x2048 bf16 = 33,554,432
  const size_t MASKB = 167772160;      // 8192x1024 bf16 = 16,777,216 (FC partials 4MB overlay)
  const size_t WIH   = 184549376;      // 3072x2048 bf16 = 12,582,912
  const size_t WHH   = 197132288;      // 2x1536x512 bf16 = 3,145,728
  const size_t WC    = 200278016;      // 4608x1024 bf16 = 9,437,184
  const size_t FCW   = 209715200;      // 2048x5632 bf16 = 23,068,672
  const size_t FEAT  = 232783872;      // 128x5632 bf16 = 1,441,792
  const size_t BIH   = 235274240;      // 3072 f32
  const size_t BNS   = 235286528;      // 2048 f32
  const size_t BNT   = 235294720;      // 2048 f32
  const size_t HB    = 235302912;      // 2x2x128x512 bf16 = 524,288
  const size_t FLG   = HB + 524288;    // 512 flags x 64B = 32,768

  float* xg   = (float*)(w + XG);
  u16*   zb16 = (u16*)(w + XG);        // overlay
  float* hs   = (float*)(w + HS);
  u16* vid    = (u16*)(w + VID);
  u16* maskb  = (u16*)(w + MASKB);
  float* fcp  = (float*)(w + MASKB);   // FC split-K partials overlay (after conv GEMM)
  u16* wih    = (u16*)(w + WIH);
  u16* whh    = (u16*)(w + WHH);
  u16* wc_    = (u16*)(w + WC);
  u16* fcw    = (u16*)(w + FCW);
  u16* feat   = (u16*)(w + FEAT);
  float* bih  = (float*)(w + BIH);
  float* bns  = (float*)(w + BNS);
  float* bnt  = (float*)(w + BNT);
  u16* hb     = (u16*)(w + HB);
  int* flg    = (int*)(w + FLG);

  // zero h double-buffer (parity0 read at t=0) + flags, every launch
  hipMemsetAsync(w + HB, 0, 524288 + 32768, stream);

  k_cvt<<<4096, 256, 0, stream>>>(videos, vid, 16777216 / 4);
  k_cvt<<<1024, 256, 0, stream>>>(Wih_f, wih, 3145728 / 4);
  k_cvt<<<1024, 256, 0, stream>>>(Wih_b, wih + 3145728, 3145728 / 4);
  k_cvt<<<512, 256, 0, stream>>>(Whh_f, whh, 786432 / 4);
  k_cvt<<<512, 256, 0, stream>>>(Whh_b, whh + 786432, 786432 / 4);
  k_cvt<<<2048, 256, 0, stream>>>(fc_w, fcw, 11534336 / 4);
  k_cvt_wc<<<2048, 256, 0, stream>>>(conv_w2, conv_w3, conv_w4, wc_);
  k_prep<<<12, 256, 0, stream>>>(bih_f, bih_b, fc_b, bn_gamma, bn_beta, bn_mean, bn_var, bih, bns, bnt);

  // xg = videos @ [Wih_f;Wih_b]^T + bih  (f32 out)
  gemm_bt<<<dim3(24, 64), 256, 0, stream>>>(vid, wih, xg, nullptr, 8192, 3072, 2048, 64, nullptr, bih);

  {
    const float* xg_c = xg; const u16* whh_c = whh;
    u16* hb_c = hb; float* hs_c = hs; int* flg_c = flg;
    const float* bf_c = bhh_f; const float* bb_c = bhh_b;
    void* args[] = { (void*)&xg_c, (void*)&whh_c, (void*)&bf_c, (void*)&bb_c,
                     (void*)&hb_c, (void*)&hs_c, (void*)&flg_c };
    hipLaunchCooperativeKernel(reinterpret_cast<void*>(gru_rec), dim3(128), dim3(512), args, 0, stream);
  }

  k_mask_pool<<<128, 256, 0, stream>>>(hs, lengths, videos_origin, motions, maskb, feat);
  // z = masked @ Wc^T  (9 shifted conv col-blocks), bf16 out
  gemm_bt<<<dim3(36, 64), 256, 0, stream>>>(maskb, wc_, nullptr, zb16, 8192, 4608, 1024, 32, nullptr, nullptr);
  k_conv_finish<<<dim3(128, 3), 512, 0, stream>>>(zb16, conv_b2, conv_b3, conv_b4, feat);
  // FC split-K x4 (raw partials; BN folded into l2norm)
  gemm_bt<<<dim3(16, 1, 4), 256, 0, stream>>>(feat, fcw, fcp, nullptr, 128, 2048, 5632, 44, nullptr, nullptr);
  k_l2norm<<<128, 256, 0, stream>>>(fcp, bns, bnt, out);
}

// Round 2
// 745.370 us; speedup vs baseline: 1.2500x; 1.2121x over previous
//
#include <hip/hip_runtime.h>
#include <hip/hip_bf16.h>
#include <stdint.h>

typedef __attribute__((ext_vector_type(8))) short short8;
typedef __attribute__((ext_vector_type(4))) float floatx4;
typedef unsigned short u16;
typedef unsigned int u32;
typedef unsigned long long u64;

static __device__ __forceinline__ u16 f2bf(float f) {
  union { float f; u32 u; } v; v.f = f;
  return (u16)((v.u + 0x7fffu + ((v.u >> 16) & 1u)) >> 16);
}
static __device__ __forceinline__ float bf2f(u16 h) {
  union { u32 u; float f; } v; v.u = ((u32)h) << 16; return v.f;
}
static __device__ __forceinline__ u64 pack4(float a, float b, float c, float d) {
  return (u64)f2bf(a) | ((u64)f2bf(b) << 16) | ((u64)f2bf(c) << 32) | ((u64)f2bf(d) << 48);
}

// ---------------- conversions ----------------
__global__ __launch_bounds__(256) void k_cvt(const float* __restrict__ src, u16* __restrict__ dst, int nquad) {
  int i = blockIdx.x * 256 + threadIdx.x;
  int stride = gridDim.x * 256;
  for (; i < nquad; i += stride) {
    float4 v = ((const float4*)src)[i];
    ((u64*)dst)[i] = pack4(v.x, v.y, v.z, v.w);
  }
}

// conv weights (K,1,ws,1024) -> Wc[4608][1024] bf16, rows = [ws2: j*512+k | ws3 | ws4]
__global__ __launch_bounds__(256) void k_cvt_wc(const float* __restrict__ w2, const float* __restrict__ w3,
                                                const float* __restrict__ w4, u16* __restrict__ wc) {
  int i = blockIdx.x * 256 + threadIdx.x;
  int stride = gridDim.x * 256;
  const int nquad = 4608 * 1024 / 4;
  for (; i < nquad; i += stride) {
    int e = i << 2;
    int row = e >> 10, col = e & 1023;
    const float* src;
    if (row < 1024)      { int j = row >> 9, k = row & 511;               src = w2 + (k * 2 + j) * 1024; }
    else if (row < 2560) { int m = row - 1024; int j = m >> 9, k = m & 511; src = w3 + (k * 3 + j) * 1024; }
    else                 { int m = row - 2560; int j = m >> 9, k = m & 511; src = w4 + (k * 4 + j) * 1024; }
    float4 v = *(const float4*)(src + col);
    ((u64*)wc)[i] = pack4(v.x, v.y, v.z, v.w);
  }
}

__global__ __launch_bounds__(256) void k_prep(const float* __restrict__ bih_f, const float* __restrict__ bih_b,
    const float* __restrict__ fcb, const float* __restrict__ gam, const float* __restrict__ bet,
    const float* __restrict__ mu, const float* __restrict__ var,
    float* __restrict__ bihcat, float* __restrict__ bns, float* __restrict__ bnt) {
  int i = blockIdx.x * 256 + threadIdx.x;
  if (i < 3072) bihcat[i] = (i < 1536) ? bih_f[i] : bih_b[i - 1536];
  if (i < 2048) {
    float s = gam[i] * rsqrtf(var[i] + 1e-5f);
    bns[i] = s;
    bnt[i] = s * (fcb[i] - mu[i]) + bet[i];
  }
}

// ---------------- generic bf16 MFMA GEMM: C[M,N] = A[M,K] * B[N,K]^T
// kn = number of 32-wide k-tiles this block processes; k-tile base = blockIdx.z * kn.
// f32 partial output goes to C + blockIdx.z*M*N (split-K); bf16 path via C16.
static __device__ __forceinline__ void gload_lds16(const u16* g, u16* l) {
  __builtin_amdgcn_global_load_lds((const __attribute__((address_space(1))) u32*)(const void*)g,
                                   (__attribute__((address_space(3))) u32*)(void*)l, 16, 0, 0);
}

__global__ __launch_bounds__(256) void gemm_bt(
    const u16* __restrict__ A, const u16* __restrict__ Bm,
    float* __restrict__ C, u16* __restrict__ C16, int M, int N, int K, int kn,
    const float* __restrict__ scale, const float* __restrict__ shift)
{
  __shared__ u16 As[128 * 32];
  __shared__ u16 Bs[128 * 32];
  int tid = threadIdx.x, lane = tid & 63, wid = tid >> 6;
  int m0 = blockIdx.y * 128, n0 = blockIdx.x * 128;
  int kt0 = blockIdx.z * kn;
  int wr = wid >> 1, wc = wid & 1;
  int r16 = lane & 15, kq = lane >> 4;
  const floatx4 z4 = {0.f, 0.f, 0.f, 0.f};
  floatx4 acc[4][4];
#pragma unroll
  for (int i = 0; i < 4; ++i)
#pragma unroll
    for (int j = 0; j < 4; ++j) acc[i][j] = z4;
  for (int kt = kt0; kt < kt0 + kn; ++kt) {
    __syncthreads();
#pragma unroll
    for (int inst = 0; inst < 2; ++inst) {
      int g = inst * 256 + tid;
      int row = g >> 2, cb = g & 3;
      const u16* ga = A + (long)(m0 + row) * K + kt * 32 + cb * 8;
      const u16* gb = Bm + (long)(n0 + row) * K + kt * 32 + cb * 8;
      gload_lds16(ga, &As[(inst * 256 + wid * 64) * 8]);
      gload_lds16(gb, &Bs[(inst * 256 + wid * 64) * 8]);
    }
    __syncthreads();
    short8 af[4], bf[4];
#pragma unroll
    for (int mt = 0; mt < 4; ++mt) af[mt] = *(const short8*)&As[(wr * 64 + mt * 16 + r16) * 32 + kq * 8];
#pragma unroll
    for (int nt = 0; nt < 4; ++nt) bf[nt] = *(const short8*)&Bs[(wc * 64 + nt * 16 + r16) * 32 + kq * 8];
#pragma unroll
    for (int mt = 0; mt < 4; ++mt)
#pragma unroll
      for (int nt = 0; nt < 4; ++nt)
        acc[mt][nt] = __builtin_amdgcn_mfma_f32_16x16x32_bf16(af[mt], bf[nt], acc[mt][nt], 0, 0, 0);
  }
  float* Cp = C + (long)blockIdx.z * M * N;
#pragma unroll
  for (int nt = 0; nt < 4; ++nt) {
    int col = n0 + wc * 64 + nt * 16 + r16;
    float sc = scale ? scale[col] : 1.f;
    float sh = shift ? shift[col] : 0.f;
#pragma unroll
    for (int mt = 0; mt < 4; ++mt)
#pragma unroll
      for (int q = 0; q < 4; ++q) {
        int row = m0 + wr * 64 + mt * 16 + kq * 4 + q;
        float v = acc[mt][nt][q] * sc + sh;
        if (C16) C16[(long)row * N + col] = f2bf(v);
        else     Cp[(long)row * N + col] = v;
      }
  }
}

// ---------------- GRU recurrence ----------------
// 128 blocks x 512 threads = dir(2) x b-tile(8 of 16 batches) x i-slice(8 of 64 i).
// Whh frags in registers. Group = 8 i-slice blocks sharing (dir, bt).
// R1 change: h-exchange loads were per-lane scattered (1KB lane stride), 4x
// ih-redundant, L2-bypassing -> ~16MB of L3 line traffic per step (L3-txn
// bound, ~16k cy/step). Now: COALESCED cooperative stage of the block's 16KB
// h-slice into LDS (thread tid loads contiguous 32B), XOR-swizzled LDS layout
// (byte ^= (row&7)<<4) so the 1KB-stride fragment reads are bank-conflict-free;
// all waves read fragments from LDS. 8x fewer L3 lines, no duplication.
// Publish protocol unchanged: ks0 drains own stores (vmcnt(0)) then publishes
// per-wave flags; wave 0 polls with s_sleep backoff; raw s_barrier release.
// Single LDS stage buffer is race-free: all fragment reads complete before the
// part-exchange barrier; next stage write happens after the next top barrier.
__global__ __launch_bounds__(512) void gru_rec(
    const float* __restrict__ xg,     // [8192][3072]
    const u16* __restrict__ whhb,     // [2][1536][512] bf16
    const float* __restrict__ bhh_f, const float* __restrict__ bhh_b,
    u16* __restrict__ hbuf,           // [2 parity][2 dir][128][512] bf16 (zeroed each launch)
    float* __restrict__ hs,           // [128][64][1024] fp32
    int* __restrict__ flg)            // 512 flags x 16 ints (64B lines), zeroed each launch
{
  __shared__ float part[2][4][3][256];
  __shared__ u16 hstage[8192];        // 16KB: h[16 batches][512 i] bf16, XOR-swizzled
  int tid = threadIdx.x, lane = tid & 63, wid = tid >> 6;
  int bid = blockIdx.x;
  int dir = bid >> 6, rem = bid & 63, bt = rem >> 3, is = rem & 7;
  int ih = wid & 3, ks = wid >> 2;
  int gbase = (dir * 8 + bt) * 32;
  int r16 = lane & 15, kq = lane >> 4;
  int iglob = is * 64 + ih * 16 + r16;       // i index of this lane's weight rows
  int i0 = is * 64 + ih * 16 + kq * 4;       // i base of this lane's 4 outputs
  int batch = bt * 16 + r16;                 // this lane's output batch (global)
  int pollidx = (gbase + (lane & 31)) * 16;
  int pubidx = (gbase + is * 4 + ih) * 16;
  const float* bhh = dir ? bhh_b : bhh_f;
  const floatx4 z4 = {0.f, 0.f, 0.f, 0.f};

  short8 wfrag[3][8];
#pragma unroll
  for (int g = 0; g < 3; ++g) {
    const u16* wrow = whhb + (long)(dir * 1536 + g * 512 + iglob) * 512;
#pragma unroll
    for (int kk = 0; kk < 8; ++kk)
      wfrag[g][kk] = *(const short8*)&wrow[(ks * 8 + kk) * 32 + kq * 8];
  }
  float4 bh4[3];
#pragma unroll
  for (int g = 0; g < 3; ++g) bh4[g] = *(const float4*)&bhh[g * 512 + i0];
  float4 hprev = {0.f, 0.f, 0.f, 0.f};

  float4 px[3];
  if (ks == 0) {
    int ts0 = dir ? 63 : 0;
    long xb = (long)(batch * 64 + ts0) * 3072 + dir * 1536 + i0;
#pragma unroll
    for (int g = 0; g < 3; ++g) px[g] = *(const float4*)&xg[xb + g * 512];
  }

  // precomputed stage/fragment LDS addressing
  int sb0 = tid * 32;                        // this thread's 32B stage chunk (linear byte)
  int ssw = ((sb0 >> 10) & 7) << 4;          // stage swizzle (row = sb0>>10)
  char* sl0 = (char*)hstage + ((sb0     ) ^ ssw);
  char* sl1 = (char*)hstage + ((sb0 + 16) ^ ssw);
  int rb = r16 * 1024 + ks * 512 + kq * 16;  // fragment base byte (row-major)
  int rsw = (r16 & 7) << 4;                  // fragment swizzle

  for (int t = 0; t < 64; ++t) {
    // 1. wait for all group blocks to have finished step t-1.
    //    Single poller wave per block + sleep backoff; raw barrier releases the rest.
    if (t > 0) {
      if (wid == 0) {
        while (true) {
          int v = __hip_atomic_load(&flg[pollidx], __ATOMIC_RELAXED, __HIP_MEMORY_SCOPE_AGENT);
          if (__all(v >= t)) break;
          __builtin_amdgcn_s_sleep(1);
        }
      }
      asm volatile("s_barrier" ::: "memory");
    }
    int par = t & 1;
    // 2. coalesced cooperative stage: h[16][512] bf16 (16KB) -> LDS (swizzled).
    //    Thread tid loads contiguous bytes [tid*32, tid*32+32) with agent scope
    //    (L3 coherence point). 32 lines/wave instead of 256 scattered.
    const u64* hsrc8 = (const u64*)(hbuf + (long)((par * 2 + dir) * 128 + bt * 16) * 512);
    u64 q0 = __hip_atomic_load(hsrc8 + tid * 4 + 0, __ATOMIC_RELAXED, __HIP_MEMORY_SCOPE_AGENT);
    u64 q1 = __hip_atomic_load(hsrc8 + tid * 4 + 1, __ATOMIC_RELAXED, __HIP_MEMORY_SCOPE_AGENT);
    u64 q2 = __hip_atomic_load(hsrc8 + tid * 4 + 2, __ATOMIC_RELAXED, __HIP_MEMORY_SCOPE_AGENT);
    u64 q3 = __hip_atomic_load(hsrc8 + tid * 4 + 3, __ATOMIC_RELAXED, __HIP_MEMORY_SCOPE_AGENT);
    // 3. issue next-step xg prefetch after stage loads (hidden under the step)
    float4 pxn[3];
    if (ks == 0 && t < 63) {
      int ts1 = dir ? (62 - t) : (t + 1);
      long xb = (long)(batch * 64 + ts1) * 3072 + dir * 1536 + i0;
#pragma unroll
      for (int g = 0; g < 3; ++g) pxn[g] = *(const float4*)&xg[xb + g * 512];
    }
    // LDS stage write (compiler inserts the vmcnt waits for q0..q3)
    ((u64*)sl0)[0] = q0; ((u64*)sl0)[1] = q1;
    ((u64*)sl1)[0] = q2; ((u64*)sl1)[1] = q3;
    asm volatile("s_waitcnt lgkmcnt(0)\n\ts_barrier" ::: "memory");
    // 4. fragments from LDS + MFMA
    floatx4 acc[3];
#pragma unroll
    for (int g = 0; g < 3; ++g) acc[g] = z4;
#pragma unroll
    for (int kk = 0; kk < 8; ++kk) {
      short8 hv = *(const short8*)((const char*)hstage + ((rb + kk * 64) ^ rsw));
#pragma unroll
      for (int g = 0; g < 3; ++g)
        acc[g] = __builtin_amdgcn_mfma_f32_16x16x32_bf16(wfrag[g][kk], hv, acc[g], 0, 0, 0);
    }
    if (ks == 1) {
#pragma unroll
      for (int g = 0; g < 3; ++g) *(floatx4*)&part[par][ih][g][lane * 4] = acc[g];
    }
    // LDS-only barrier: order ks1 ds_writes before ks0 ds_reads; no vmcnt drain.
    asm volatile("s_waitcnt lgkmcnt(0)\n\ts_barrier" ::: "memory");
    if (ks == 0) {
      int tsrc = dir ? (63 - t) : t;
#pragma unroll
      for (int g = 0; g < 3; ++g) acc[g] += *(const floatx4*)&part[par][ih][g][lane * 4];
      float4 hn4;
#pragma unroll
      for (int q = 0; q < 4; ++q) {
        float rr = acc[0][q] + ((const float*)&bh4[0])[q] + ((const float*)&px[0])[q];
        float zz = acc[1][q] + ((const float*)&bh4[1])[q] + ((const float*)&px[1])[q];
        float r = 1.f / (1.f + __expf(-rr));
        float z = 1.f / (1.f + __expf(-zz));
        float n = tanhf(((const float*)&px[2])[q] + r * (acc[2][q] + ((const float*)&bh4[2])[q]));
        ((float*)&hn4)[q] = (1.f - z) * n + z * ((const float*)&hprev)[q];
      }
      hprev = hn4;
      u16* hdst = hbuf + (long)(((par ^ 1) * 2 + dir) * 128 + bt * 16) * 512;
      __hip_atomic_store((u64*)&hdst[r16 * 512 + i0], pack4(hn4.x, hn4.y, hn4.z, hn4.w),
                         __ATOMIC_RELAXED, __HIP_MEMORY_SCOPE_AGENT);
      if (t < 63) {
        // drain own stores (h store; xg prefetch is ~1500cy old by now), then publish
        asm volatile("s_waitcnt vmcnt(0)" ::: "memory");
        if (lane == 0)
          __hip_atomic_store(&flg[pubidx], t + 1, __ATOMIC_RELAXED, __HIP_MEMORY_SCOPE_AGENT);
      }
      // hs store off the critical path (drains at next step's vmcnt(0))
      *(float4*)&hs[(long)(batch * 64 + tsrc) * 1024 + dir * 512 + i0] = hn4;
      px[0] = pxn[0]; px[1] = pxn[1]; px[2] = pxn[2];
    }
  }
}

// ---------------- mask + mean-pool + feature assembly ----------------
__global__ __launch_bounds__(256) void k_mask_pool(
    const float* __restrict__ hs, const int* __restrict__ lengths,
    const float* __restrict__ vo, const float* __restrict__ mo,
    u16* __restrict__ maskedb, u16* __restrict__ feat)
{
  int b = blockIdx.x, tid = threadIdx.x;
  int len = lengths[b];
  float inv = 1.0f / (float)len;
  int c0 = tid * 4;
  float s0 = 0.f, s1 = 0.f, s2 = 0.f, s3 = 0.f;
  for (int t = 0; t < 64; ++t) {
    float4 v = *(const float4*)&hs[(long)(b * 64 + t) * 1024 + c0];
    u64 pk = 0ull;
    if (t < len) {
      s0 += v.x; s1 += v.y; s2 += v.z; s3 += v.w;
      pk = pack4(v.x, v.y, v.z, v.w);
    }
    *(u64*)&maskedb[(long)(b * 64 + t) * 1024 + c0] = pk;
  }
  u16* fb = feat + (long)b * 5632;
  *(u64*)&fb[c0] = pack4(s0 * inv, s1 * inv, s2 * inv, s3 * inv);
  {
    int c = tid * 8;
    float4 a = *(const float4*)&vo[(long)b * 2048 + c];
    float4 d = *(const float4*)&vo[(long)b * 2048 + c + 4];
    *(u64*)&fb[2560 + c] = pack4(a.x, a.y, a.z, a.w);
    *(u64*)&fb[2560 + c + 4] = pack4(d.x, d.y, d.z, d.w);
  }
  {
    float4 a = *(const float4*)&mo[(long)b * 1024 + c0];
    *(u64*)&fb[4608 + c0] = pack4(a.x, a.y, a.z, a.w);
  }
}

// ---------------- conv shift-add + relu + max over positions (z is bf16) ----------------
__global__ __launch_bounds__(512) void k_conv_finish(
    const u16* __restrict__ z, const float* __restrict__ cb2,
    const float* __restrict__ cb3, const float* __restrict__ cb4,
    u16* __restrict__ feat)
{
  int b = blockIdx.x, wsi = blockIdx.y, k = threadIdx.x;
  int ws = wsi + 2;
  int base = (wsi == 0) ? 0 : (wsi == 1 ? 1024 : 2560);
  const float* cb = (wsi == 0) ? cb2 : (wsi == 1 ? cb3 : cb4);
  float bias = cb[k];
  float m = 0.f;  // relu floor
  for (int p = 0; p < 64 + ws - 1; ++p) {
    float acc = bias;
    for (int j = 0; j < ws; ++j) {
      int t = p - (ws - 1) + j;
      if (t >= 0 && t < 64)
        acc += bf2f(z[(long)(b * 64 + t) * 4608 + base + j * 512 + k]);
    }
    m = fmaxf(m, acc);
  }
  feat[(long)b * 5632 + 1024 + wsi * 512 + k] = f2bf(m);
}

// ---------------- split-K reduce + BN + row L2 normalize ----------------
__global__ __launch_bounds__(256) void k_l2norm(const float* __restrict__ p,
    const float* __restrict__ bns, const float* __restrict__ bnt, float* __restrict__ out)
{
  __shared__ float red[4];
  int b = blockIdx.x, tid = threadIdx.x;
  float v[8]; float s = 0.f;
#pragma unroll
  for (int j = 0; j < 8; ++j) {
    int i = j * 256 + tid;
    long o = (long)b * 2048 + i;
    float a = p[o] + p[o + 262144] + p[o + 524288] + p[o + 786432];
    a = a * bns[i] + bnt[i];
    v[j] = a; s += a * a;
  }
#pragma unroll
  for (int o = 32; o > 0; o >>= 1) s += __shfl_down(s, o);
  if ((tid & 63) == 0) red[tid >> 6] = s;
  __syncthreads();
  float rn = rsqrtf(red[0] + red[1] + red[2] + red[3]);
#pragma unroll
  for (int j = 0; j < 8; ++j)
    out[(long)b * 2048 + j * 256 + tid] = v[j] * rn;
}

// ---------------- launch ----------------
extern "C" void kernel_launch(void* const* d_in, const int* in_sizes, int n_in,
                              void* d_out, int out_size, void* d_ws, size_t ws_size,
                              hipStream_t stream)
{
  (void)in_sizes; (void)n_in; (void)out_size; (void)ws_size;
  const float* videos       = (const float*)d_in[0];
  const float* motions      = (const float*)d_in[1];
  const float* videos_origin= (const float*)d_in[2];
  const int*   lengths      = (const int*)d_in[3];
  const float* Wih_f = (const float*)d_in[4];
  const float* Whh_f = (const float*)d_in[5];
  const float* bih_f = (const float*)d_in[6];
  const float* bhh_f = (const float*)d_in[7];
  const float* Wih_b = (const float*)d_in[8];
  const float* Whh_b = (const float*)d_in[9];
  const float* bih_b = (const float*)d_in[10];
  const float* bhh_b = (const float*)d_in[11];
  const float* fc_w  = (const float*)d_in[12];
  const float* fc_b  = (const float*)d_in[13];
  const float* bn_gamma = (const float*)d_in[14];
  const float* bn_beta  = (const float*)d_in[15];
  const float* bn_mean  = (const float*)d_in[16];
  const float* bn_var   = (const float*)d_in[17];
  const float* conv_w2 = (const float*)d_in[18];
  const float* conv_b2 = (const float*)d_in[19];
  const float* conv_w3 = (const float*)d_in[20];
  const float* conv_b3 = (const float*)d_in[21];
  const float* conv_w4 = (const float*)d_in[22];
  const float* conv_b4 = (const float*)d_in[23];
  float* out = (float*)d_out;
  char* w = (char*)d_ws;

  // workspace layout (bytes). z (bf16) overlays XG; FC split-K partials overlay MASKB.
  const size_t XG    = 0;              // 8192x3072 f32 = 100,663,296
  const size_t HS    = 100663296;      // 128x64x1024 f32 = 33,554,432
  const size_t VID   = 134217728;      // 8192x2048 bf16 = 33,554,432
  const size_t MASKB = 167772160;      // 8192x1024 bf16 = 16,777,216 (FC partials 4MB overlay)
  const size_t WIH   = 184549376;      // 3072x2048 bf16 = 12,582,912
  const size_t WHH   = 197132288;      // 2x1536x512 bf16 = 3,145,728
  const size_t WC    = 200278016;      // 4608x1024 bf16 = 9,437,184
  const size_t FCW   = 209715200;      // 2048x5632 bf16 = 23,068,672
  const size_t FEAT  = 232783872;      // 128x5632 bf16 = 1,441,792
  const size_t BIH   = 235274240;      // 3072 f32
  const size_t BNS   = 235286528;      // 2048 f32
  const size_t BNT   = 235294720;      // 2048 f32
  const size_t HB    = 235302912;      // 2x2x128x512 bf16 = 524,288
  const size_t FLG   = HB + 524288;    // 512 flags x 64B = 32,768

  float* xg   = (float*)(w + XG);
  u16*   zb16 = (u16*)(w + XG);        // overlay
  float* hs   = (float*)(w + HS);
  u16* vid    = (u16*)(w + VID);
  u16* maskb  = (u16*)(w + MASKB);
  float* fcp  = (float*)(w + MASKB);   // FC split-K partials overlay (after conv GEMM)
  u16* wih    = (u16*)(w + WIH);
  u16* whh    = (u16*)(w + WHH);
  u16* wc_    = (u16*)(w + WC);
  u16* fcw    = (u16*)(w + FCW);
  u16* feat   = (u16*)(w + FEAT);
  float* bih  = (float*)(w + BIH);
  float* bns  = (float*)(w + BNS);
  float* bnt  = (float*)(w + BNT);
  u16* hb     = (u16*)(w + HB);
  int* flg    = (int*)(w + FLG);

  // zero h double-buffer (parity0 read at t=0) + flags, every launch
  hipMemsetAsync(w + HB, 0, 524288 + 32768, stream);

  k_cvt<<<4096, 256, 0, stream>>>(videos, vid, 16777216 / 4);
  k_cvt<<<1024, 256, 0, stream>>>(Wih_f, wih, 3145728 / 4);
  k_cvt<<<1024, 256, 0, stream>>>(Wih_b, wih + 3145728, 3145728 / 4);
  k_cvt<<<512, 256, 0, stream>>>(Whh_f, whh, 786432 / 4);
  k_cvt<<<512, 256, 0, stream>>>(Whh_b, whh + 786432, 786432 / 4);
  k_cvt<<<2048, 256, 0, stream>>>(fc_w, fcw, 11534336 / 4);
  k_cvt_wc<<<2048, 256, 0, stream>>>(conv_w2, conv_w3, conv_w4, wc_);
  k_prep<<<12, 256, 0, stream>>>(bih_f, bih_b, fc_b, bn_gamma, bn_beta, bn_mean, bn_var, bih, bns, bnt);

  // xg = videos @ [Wih_f;Wih_b]^T + bih  (f32 out)
  gemm_bt<<<dim3(24, 64), 256, 0, stream>>>(vid, wih, xg, nullptr, 8192, 3072, 2048, 64, nullptr, bih);

  {
    const float* xg_c = xg; const u16* whh_c = whh;
    u16* hb_c = hb; float* hs_c = hs; int* flg_c = flg;
    const float* bf_c = bhh_f; const float* bb_c = bhh_b;
    void* args[] = { (void*)&xg_c, (void*)&whh_c, (void*)&bf_c, (void*)&bb_c,
                     (void*)&hb_c, (void*)&hs_c, (void*)&flg_c };
    hipLaunchCooperativeKernel(reinterpret_cast<void*>(gru_rec), dim3(128), dim3(512), args, 0, stream);
  }

  k_mask_pool<<<128, 256, 0, stream>>>(hs, lengths, videos_origin, motions, maskb, feat);
  // z = masked @ Wc^T  (9 shifted conv col-blocks), bf16 out
  gemm_bt<<<dim3(36, 64), 256, 0, stream>>>(maskb, wc_, nullptr, zb16, 8192, 4608, 1024, 32, nullptr, nullptr);
  k_conv_finish<<<dim3(128, 3), 512, 0, stream>>>(zb16, conv_b2, conv_b3, conv_b4, feat);
  // FC split-K x4 (raw partials; BN folded into l2norm)
  gemm_bt<<<dim3(16, 1, 4), 256, 0, stream>>>(feat, fcw, fcp, nullptr, 128, 2048, 5632, 44, nullptr, nullptr);
  k_l2norm<<<128, 256, 0, stream>>>(fcp, bns, bnt, out);
}

// Round 3
// 700.013 us; speedup vs baseline: 1.3310x; 1.0648x over previous
//
#include <hip/hip_runtime.h>
#include <hip/hip_bf16.h>
#include <stdint.h>

typedef __attribute__((ext_vector_type(8))) short short8;
typedef __attribute__((ext_vector_type(4))) float floatx4;
typedef __attribute__((ext_vector_type(4))) unsigned int u32x4;
typedef unsigned short u16;
typedef unsigned int u32;
typedef unsigned long long u64;

static __device__ __forceinline__ u16 f2bf(float f) {
  union { float f; u32 u; } v; v.f = f;
  return (u16)((v.u + 0x7fffu + ((v.u >> 16) & 1u)) >> 16);
}
static __device__ __forceinline__ float bf2f(u16 h) {
  union { u32 u; float f; } v; v.u = ((u32)h) << 16; return v.f;
}
static __device__ __forceinline__ u64 pack4(float a, float b, float c, float d) {
  return (u64)f2bf(a) | ((u64)f2bf(b) << 16) | ((u64)f2bf(c) << 32) | ((u64)f2bf(d) << 48);
}

// ---------------- conversions ----------------
__global__ __launch_bounds__(256) void k_cvt(const float* __restrict__ src, u16* __restrict__ dst, int nquad) {
  int i = blockIdx.x * 256 + threadIdx.x;
  int stride = gridDim.x * 256;
  for (; i < nquad; i += stride) {
    float4 v = ((const float4*)src)[i];
    ((u64*)dst)[i] = pack4(v.x, v.y, v.z, v.w);
  }
}

// conv weights (K,1,ws,1024) -> Wc[4608][1024] bf16, rows = [ws2: j*512+k | ws3 | ws4]
__global__ __launch_bounds__(256) void k_cvt_wc(const float* __restrict__ w2, const float* __restrict__ w3,
                                                const float* __restrict__ w4, u16* __restrict__ wc) {
  int i = blockIdx.x * 256 + threadIdx.x;
  int stride = gridDim.x * 256;
  const int nquad = 4608 * 1024 / 4;
  for (; i < nquad; i += stride) {
    int e = i << 2;
    int row = e >> 10, col = e & 1023;
    const float* src;
    if (row < 1024)      { int j = row >> 9, k = row & 511;               src = w2 + (k * 2 + j) * 1024; }
    else if (row < 2560) { int m = row - 1024; int j = m >> 9, k = m & 511; src = w3 + (k * 3 + j) * 1024; }
    else                 { int m = row - 2560; int j = m >> 9, k = m & 511; src = w4 + (k * 4 + j) * 1024; }
    float4 v = *(const float4*)(src + col);
    ((u64*)wc)[i] = pack4(v.x, v.y, v.z, v.w);
  }
}

__global__ __launch_bounds__(256) void k_prep(const float* __restrict__ bih_f, const float* __restrict__ bih_b,
    const float* __restrict__ fcb, const float* __restrict__ gam, const float* __restrict__ bet,
    const float* __restrict__ mu, const float* __restrict__ var,
    float* __restrict__ bihcat, float* __restrict__ bns, float* __restrict__ bnt) {
  int i = blockIdx.x * 256 + threadIdx.x;
  if (i < 3072) bihcat[i] = (i < 1536) ? bih_f[i] : bih_b[i - 1536];
  if (i < 2048) {
    float s = gam[i] * rsqrtf(var[i] + 1e-5f);
    bns[i] = s;
    bnt[i] = s * (fcb[i] - mu[i]) + bet[i];
  }
}

// ---------------- generic bf16 MFMA GEMM: C[M,N] = A[M,K] * B[N,K]^T
// kn = number of 32-wide k-tiles this block processes; k-tile base = blockIdx.z * kn.
// f32 partial output goes to C + blockIdx.z*M*N (split-K); bf16 path via C16.
static __device__ __forceinline__ void gload_lds16(const u16* g, u16* l) {
  __builtin_amdgcn_global_load_lds((const __attribute__((address_space(1))) u32*)(const void*)g,
                                   (__attribute__((address_space(3))) u32*)(void*)l, 16, 0, 0);
}

__global__ __launch_bounds__(256) void gemm_bt(
    const u16* __restrict__ A, const u16* __restrict__ Bm,
    float* __restrict__ C, u16* __restrict__ C16, int M, int N, int K, int kn,
    const float* __restrict__ scale, const float* __restrict__ shift)
{
  __shared__ u16 As[128 * 32];
  __shared__ u16 Bs[128 * 32];
  int tid = threadIdx.x, lane = tid & 63, wid = tid >> 6;
  int m0 = blockIdx.y * 128, n0 = blockIdx.x * 128;
  int kt0 = blockIdx.z * kn;
  int wr = wid >> 1, wc = wid & 1;
  int r16 = lane & 15, kq = lane >> 4;
  const floatx4 z4 = {0.f, 0.f, 0.f, 0.f};
  floatx4 acc[4][4];
#pragma unroll
  for (int i = 0; i < 4; ++i)
#pragma unroll
    for (int j = 0; j < 4; ++j) acc[i][j] = z4;
  for (int kt = kt0; kt < kt0 + kn; ++kt) {
    __syncthreads();
#pragma unroll
    for (int inst = 0; inst < 2; ++inst) {
      int g = inst * 256 + tid;
      int row = g >> 2, cb = g & 3;
      const u16* ga = A + (long)(m0 + row) * K + kt * 32 + cb * 8;
      const u16* gb = Bm + (long)(n0 + row) * K + kt * 32 + cb * 8;
      gload_lds16(ga, &As[(inst * 256 + wid * 64) * 8]);
      gload_lds16(gb, &Bs[(inst * 256 + wid * 64) * 8]);
    }
    __syncthreads();
    short8 af[4], bf[4];
#pragma unroll
    for (int mt = 0; mt < 4; ++mt) af[mt] = *(const short8*)&As[(wr * 64 + mt * 16 + r16) * 32 + kq * 8];
#pragma unroll
    for (int nt = 0; nt < 4; ++nt) bf[nt] = *(const short8*)&Bs[(wc * 64 + nt * 16 + r16) * 32 + kq * 8];
#pragma unroll
    for (int mt = 0; mt < 4; ++mt)
#pragma unroll
      for (int nt = 0; nt < 4; ++nt)
        acc[mt][nt] = __builtin_amdgcn_mfma_f32_16x16x32_bf16(af[mt], bf[nt], acc[mt][nt], 0, 0, 0);
  }
  float* Cp = C + (long)blockIdx.z * M * N;
#pragma unroll
  for (int nt = 0; nt < 4; ++nt) {
    int col = n0 + wc * 64 + nt * 16 + r16;
    float sc = scale ? scale[col] : 1.f;
    float sh = shift ? shift[col] : 0.f;
#pragma unroll
    for (int mt = 0; mt < 4; ++mt)
#pragma unroll
      for (int q = 0; q < 4; ++q) {
        int row = m0 + wr * 64 + mt * 16 + kq * 4 + q;
        float v = acc[mt][nt][q] * sc + sh;
        if (C16) C16[(long)row * N + col] = f2bf(v);
        else     Cp[(long)row * N + col] = v;
      }
  }
}

// ---------------- GRU recurrence ----------------
// 128 blocks x 512 threads = dir(2) x b-tile(8 of 16 batches) x i-slice(8 of 64 i).
// R2 changes:
// (a) All cross-block handshake traffic (hbuf stores/loads, flag store/poll)
//     now uses explicit `sc0 sc1` (NO nt) inline-asm global ops. R1 counters
//     showed WRITE_SIZE = 50MB = hs(33.5) + hbuf(16) -> the HIP agent-scope
//     atomics were STREAMING hbuf to HBM, so every handshake hop paid ~1100cy
//     HBM latency (3-4 RTs ~= measured 4.1us/step). sc0 sc1 without nt keeps
//     the lines allocated in L3 (agent coherence point) -> ~500cy hops.
// (b) Stage write bank conflict fix (R1: 3.1M conflicts): each thread now
//     stages two 16B chunks at wid*2048+lane*16 and +1024 (granule = lane&7,
//     conflict-free) instead of one 32B chunk (granule always even, 2-way).
// Ordering: all asm volatile with "memory" clobber; explicit vmcnt(0) between
// stage loads and LDS writes, and between h-store and flag publish.
__global__ __launch_bounds__(512) void gru_rec(
    const float* __restrict__ xg,     // [8192][3072]
    const u16* __restrict__ whhb,     // [2][1536][512] bf16
    const float* __restrict__ bhh_f, const float* __restrict__ bhh_b,
    u16* __restrict__ hbuf,           // [2 parity][2 dir][128][512] bf16 (zeroed each launch)
    float* __restrict__ hs,           // [128][64][1024] fp32
    int* __restrict__ flg)            // 512 flags x 16 ints (64B lines), zeroed each launch
{
  __shared__ float part[2][4][3][256];
  __shared__ u16 hstage[8192];        // 16KB: h[16 batches][512 i] bf16, XOR-swizzled
  int tid = threadIdx.x, lane = tid & 63, wid = tid >> 6;
  int bid = blockIdx.x;
  int dir = bid >> 6, rem = bid & 63, bt = rem >> 3, is = rem & 7;
  int ih = wid & 3, ks = wid >> 2;
  int gbase = (dir * 8 + bt) * 32;
  int r16 = lane & 15, kq = lane >> 4;
  int iglob = is * 64 + ih * 16 + r16;       // i index of this lane's weight rows
  int i0 = is * 64 + ih * 16 + kq * 4;       // i base of this lane's 4 outputs
  int batch = bt * 16 + r16;                 // this lane's output batch (global)
  int pollidx = (gbase + (lane & 31)) * 16;
  int pubidx = (gbase + is * 4 + ih) * 16;
  const float* bhh = dir ? bhh_b : bhh_f;
  const floatx4 z4 = {0.f, 0.f, 0.f, 0.f};

  short8 wfrag[3][8];
#pragma unroll
  for (int g = 0; g < 3; ++g) {
    const u16* wrow = whhb + (long)(dir * 1536 + g * 512 + iglob) * 512;
#pragma unroll
    for (int kk = 0; kk < 8; ++kk)
      wfrag[g][kk] = *(const short8*)&wrow[(ks * 8 + kk) * 32 + kq * 8];
  }
  float4 bh4[3];
#pragma unroll
  for (int g = 0; g < 3; ++g) bh4[g] = *(const float4*)&bhh[g * 512 + i0];
  float4 hprev = {0.f, 0.f, 0.f, 0.f};

  float4 px[3];
  if (ks == 0) {
    int ts0 = dir ? 63 : 0;
    long xb = (long)(batch * 64 + ts0) * 3072 + dir * 1536 + i0;
#pragma unroll
    for (int g = 0; g < 3; ++g) px[g] = *(const float4*)&xg[xb + g * 512];
  }

  // stage addressing: two 16B chunks per thread, row-split for conflict-free LDS.
  // row = byte>>10 (batch index). swizzle byte ^= (row&7)<<4 matches fragment reads.
  int so0 = wid * 2048 + lane * 16;          // row 2*wid
  int so1 = so0 + 1024;                      // row 2*wid+1
  char* sl0 = (char*)hstage + (so0 ^ (((so0 >> 10) & 7) << 4));
  char* sl1 = (char*)hstage + (so1 ^ (((so1 >> 10) & 7) << 4));
  int rb = r16 * 1024 + ks * 512 + kq * 16;  // fragment base byte (row-major)
  int rsw = (r16 & 7) << 4;                  // fragment swizzle

  for (int t = 0; t < 64; ++t) {
    // 1. wait for all group blocks to have finished step t-1.
    //    Single poller wave per block + sleep backoff; raw barrier releases the rest.
    if (t > 0) {
      if (wid == 0) {
        while (true) {
          int v;
          asm volatile("global_load_dword %0, %1, off sc0 sc1\n\ts_waitcnt vmcnt(0)"
                       : "=v"(v) : "v"(&flg[pollidx]) : "memory");
          if (__all(v >= t)) break;
          __builtin_amdgcn_s_sleep(1);
        }
      }
      asm volatile("s_barrier" ::: "memory");
    }
    int par = t & 1;
    // 2. coalesced cooperative stage: h[16][512] bf16 (16KB) -> LDS (swizzled).
    //    sc0 sc1 (no nt): L1/L2-bypass for cross-XCD coherence, L3-allocating.
    const char* hsrc = (const char*)(hbuf + (long)((par * 2 + dir) * 128 + bt * 16) * 512);
    u32x4 qa, qb;
    asm volatile(
      "global_load_dwordx4 %0, %2, off sc0 sc1\n\t"
      "global_load_dwordx4 %1, %3, off sc0 sc1"
      : "=&v"(qa), "=&v"(qb)
      : "v"(hsrc + so0), "v"(hsrc + so1)
      : "memory");
    asm volatile("s_waitcnt vmcnt(0)" ::: "memory");
    *(u32x4*)sl0 = qa;
    *(u32x4*)sl1 = qb;
    // 3. next-step xg prefetch (plain cached loads); issued after the stage
    //    vmcnt drain so it never sits on the stage critical path; consumed at
    //    next step's gates (~2us later >> HBM latency).
    float4 pxn[3];
    if (ks == 0 && t < 63) {
      int ts1 = dir ? (62 - t) : (t + 1);
      long xb = (long)(batch * 64 + ts1) * 3072 + dir * 1536 + i0;
#pragma unroll
      for (int g = 0; g < 3; ++g) pxn[g] = *(const float4*)&xg[xb + g * 512];
    }
    asm volatile("s_waitcnt lgkmcnt(0)\n\ts_barrier" ::: "memory");
    // 4. fragments from LDS + MFMA
    floatx4 acc[3];
#pragma unroll
    for (int g = 0; g < 3; ++g) acc[g] = z4;
#pragma unroll
    for (int kk = 0; kk < 8; ++kk) {
      short8 hv = *(const short8*)((const char*)hstage + ((rb + kk * 64) ^ rsw));
#pragma unroll
      for (int g = 0; g < 3; ++g)
        acc[g] = __builtin_amdgcn_mfma_f32_16x16x32_bf16(wfrag[g][kk], hv, acc[g], 0, 0, 0);
    }
    if (ks == 1) {
#pragma unroll
      for (int g = 0; g < 3; ++g) *(floatx4*)&part[par][ih][g][lane * 4] = acc[g];
    }
    // LDS-only barrier: order ks1 ds_writes before ks0 ds_reads; no vmcnt drain.
    asm volatile("s_waitcnt lgkmcnt(0)\n\ts_barrier" ::: "memory");
    if (ks == 0) {
      int tsrc = dir ? (63 - t) : t;
#pragma unroll
      for (int g = 0; g < 3; ++g) acc[g] += *(const floatx4*)&part[par][ih][g][lane * 4];
      float4 hn4;
#pragma unroll
      for (int q = 0; q < 4; ++q) {
        float rr = acc[0][q] + ((const float*)&bh4[0])[q] + ((const float*)&px[0])[q];
        float zz = acc[1][q] + ((const float*)&bh4[1])[q] + ((const float*)&px[1])[q];
        float r = 1.f / (1.f + __expf(-rr));
        float z = 1.f / (1.f + __expf(-zz));
        float n = tanhf(((const float*)&px[2])[q] + r * (acc[2][q] + ((const float*)&bh4[2])[q]));
        ((float*)&hn4)[q] = (1.f - z) * n + z * ((const float*)&hprev)[q];
      }
      hprev = hn4;
      u16* hdst = hbuf + (long)(((par ^ 1) * 2 + dir) * 128 + bt * 16) * 512;
      u64 hval = pack4(hn4.x, hn4.y, hn4.z, hn4.w);
      asm volatile("global_store_dwordx2 %0, %1, off sc0 sc1"
                   :: "v"((u64*)&hdst[r16 * 512 + i0]), "v"(hval) : "memory");
      if (t < 63) {
        // drain own stores (h store), then publish flag (also sc0 sc1, L3-resident)
        asm volatile("s_waitcnt vmcnt(0)" ::: "memory");
        if (lane == 0) {
          int tv = t + 1;
          asm volatile("global_store_dword %0, %1, off sc0 sc1"
                       :: "v"(&flg[pubidx]), "v"(tv) : "memory");
        }
      }
      // hs store off the critical path (drains at next step's vmcnt(0))
      *(float4*)&hs[(long)(batch * 64 + tsrc) * 1024 + dir * 512 + i0] = hn4;
      px[0] = pxn[0]; px[1] = pxn[1]; px[2] = pxn[2];
    }
  }
}

// ---------------- mask + mean-pool + feature assembly ----------------
__global__ __launch_bounds__(256) void k_mask_pool(
    const float* __restrict__ hs, const int* __restrict__ lengths,
    const float* __restrict__ vo, const float* __restrict__ mo,
    u16* __restrict__ maskedb, u16* __restrict__ feat)
{
  int b = blockIdx.x, tid = threadIdx.x;
  int len = lengths[b];
  float inv = 1.0f / (float)len;
  int c0 = tid * 4;
  float s0 = 0.f, s1 = 0.f, s2 = 0.f, s3 = 0.f;
  for (int t = 0; t < 64; ++t) {
    float4 v = *(const float4*)&hs[(long)(b * 64 + t) * 1024 + c0];
    u64 pk = 0ull;
    if (t < len) {
      s0 += v.x; s1 += v.y; s2 += v.z; s3 += v.w;
      pk = pack4(v.x, v.y, v.z, v.w);
    }
    *(u64*)&maskedb[(long)(b * 64 + t) * 1024 + c0] = pk;
  }
  u16* fb = feat + (long)b * 5632;
  *(u64*)&fb[c0] = pack4(s0 * inv, s1 * inv, s2 * inv, s3 * inv);
  {
    int c = tid * 8;
    float4 a = *(const float4*)&vo[(long)b * 2048 + c];
    float4 d = *(const float4*)&vo[(long)b * 2048 + c + 4];
    *(u64*)&fb[2560 + c] = pack4(a.x, a.y, a.z, a.w);
    *(u64*)&fb[2560 + c + 4] = pack4(d.x, d.y, d.z, d.w);
  }
  {
    float4 a = *(const float4*)&mo[(long)b * 1024 + c0];
    *(u64*)&fb[4608 + c0] = pack4(a.x, a.y, a.z, a.w);
  }
}

// ---------------- conv shift-add + relu + max over positions (z is bf16) ----------------
__global__ __launch_bounds__(512) void k_conv_finish(
    const u16* __restrict__ z, const float* __restrict__ cb2,
    const float* __restrict__ cb3, const float* __restrict__ cb4,
    u16* __restrict__ feat)
{
  int b = blockIdx.x, wsi = blockIdx.y, k = threadIdx.x;
  int ws = wsi + 2;
  int base = (wsi == 0) ? 0 : (wsi == 1 ? 1024 : 2560);
  const float* cb = (wsi == 0) ? cb2 : (wsi == 1 ? cb3 : cb4);
  float bias = cb[k];
  float m = 0.f;  // relu floor
  for (int p = 0; p < 64 + ws - 1; ++p) {
    float acc = bias;
    for (int j = 0; j < ws; ++j) {
      int t = p - (ws - 1) + j;
      if (t >= 0 && t < 64)
        acc += bf2f(z[(long)(b * 64 + t) * 4608 + base + j * 512 + k]);
    }
    m = fmaxf(m, acc);
  }
  feat[(long)b * 5632 + 1024 + wsi * 512 + k] = f2bf(m);
}

// ---------------- split-K reduce + BN + row L2 normalize ----------------
__global__ __launch_bounds__(256) void k_l2norm(const float* __restrict__ p,
    const float* __restrict__ bns, const float* __restrict__ bnt, float* __restrict__ out)
{
  __shared__ float red[4];
  int b = blockIdx.x, tid = threadIdx.x;
  float v[8]; float s = 0.f;
#pragma unroll
  for (int j = 0; j < 8; ++j) {
    int i = j * 256 + tid;
    long o = (long)b * 2048 + i;
    float a = p[o] + p[o + 262144] + p[o + 524288] + p[o + 786432];
    a = a * bns[i] + bnt[i];
    v[j] = a; s += a * a;
  }
#pragma unroll
  for (int o = 32; o > 0; o >>= 1) s += __shfl_down(s, o);
  if ((tid & 63) == 0) red[tid >> 6] = s;
  __syncthreads();
  float rn = rsqrtf(red[0] + red[1] + red[2] + red[3]);
#pragma unroll
  for (int j = 0; j < 8; ++j)
    out[(long)b * 2048 + j * 256 + tid] = v[j] * rn;
}

// ---------------- launch ----------------
extern "C" void kernel_launch(void* const* d_in, const int* in_sizes, int n_in,
                              void* d_out, int out_size, void* d_ws, size_t ws_size,
                              hipStream_t stream)
{
  (void)in_sizes; (void)n_in; (void)out_size; (void)ws_size;
  const float* videos       = (const float*)d_in[0];
  const float* motions      = (const float*)d_in[1];
  const float* videos_origin= (const float*)d_in[2];
  const int*   lengths      = (const int*)d_in[3];
  const float* Wih_f = (const float*)d_in[4];
  const float* Whh_f = (const float*)d_in[5];
  const float* bih_f = (const float*)d_in[6];
  const float* bhh_f = (const float*)d_in[7];
  const float* Wih_b = (const float*)d_in[8];
  const float* Whh_b = (const float*)d_in[9];
  const float* bih_b = (const float*)d_in[10];
  const float* bhh_b = (const float*)d_in[11];
  const float* fc_w  = (const float*)d_in[12];
  const float* fc_b  = (const float*)d_in[13];
  const float* bn_gamma = (const float*)d_in[14];
  const float* bn_beta  = (const float*)d_in[15];
  const float* bn_mean  = (const float*)d_in[16];
  const float* bn_var   = (const float*)d_in[17];
  const float* conv_w2 = (const float*)d_in[18];
  const float* conv_b2 = (const float*)d_in[19];
  const float* conv_w3 = (const float*)d_in[20];
  const float* conv_b3 = (const float*)d_in[21];
  const float* conv_w4 = (const float*)d_in[22];
  const float* conv_b4 = (const float*)d_in[23];
  float* out = (float*)d_out;
  char* w = (char*)d_ws;

  // workspace layout (bytes). z (bf16) overlays XG; FC split-K partials overlay MASKB.
  const size_t XG    = 0;              // 8192x3072 f32 = 100,663,296
  const size_t HS    = 100663296;      // 128x64x1024 f32 = 33,554,432
  const size_t VID   = 134217728;      // 8192x2048 bf16 = 33,554,432
  const size_t MASKB = 167772160;      // 8192x1024 bf16 = 16,777,216 (FC partials 4MB overlay)
  const size_t WIH   = 184549376;      // 3072x2048 bf16 = 12,582,912
  const size_t WHH   = 197132288;      // 2x1536x512 bf16 = 3,145,728
  const size_t WC    = 200278016;      // 4608x1024 bf16 = 9,437,184
  const size_t FCW   = 209715200;      // 2048x5632 bf16 = 23,068,672
  const size_t FEAT  = 232783872;      // 128x5632 bf16 = 1,441,792
  const size_t BIH   = 235274240;      // 3072 f32
  const size_t BNS   = 235286528;      // 2048 f32
  const size_t BNT   = 235294720;      // 2048 f32
  const size_t HB    = 235302912;      // 2x2x128x512 bf16 = 524,288
  const size_t FLG   = HB + 524288;    // 512 flags x 64B = 32,768

  float* xg   = (float*)(w + XG);
  u16*   zb16 = (u16*)(w + XG);        // overlay
  float* hs   = (float*)(w + HS);
  u16* vid    = (u16*)(w + VID);
  u16* maskb  = (u16*)(w + MASKB);
  float* fcp  = (float*)(w + MASKB);   // FC split-K partials overlay (after conv GEMM)
  u16* wih    = (u16*)(w + WIH);
  u16* whh    = (u16*)(w + WHH);
  u16* wc_    = (u16*)(w + WC);
  u16* fcw    = (u16*)(w + FCW);
  u16* feat   = (u16*)(w + FEAT);
  float* bih  = (float*)(w + BIH);
  float* bns  = (float*)(w + BNS);
  float* bnt  = (float*)(w + BNT);
  u16* hb     = (u16*)(w + HB);
  int* flg    = (int*)(w + FLG);

  // zero h double-buffer (parity0 read at t=0) + flags, every launch
  hipMemsetAsync(w + HB, 0, 524288 + 32768, stream);

  k_cvt<<<4096, 256, 0, stream>>>(videos, vid, 16777216 / 4);
  k_cvt<<<1024, 256, 0, stream>>>(Wih_f, wih, 3145728 / 4);
  k_cvt<<<1024, 256, 0, stream>>>(Wih_b, wih + 3145728, 3145728 / 4);
  k_cvt<<<512, 256, 0, stream>>>(Whh_f, whh, 786432 / 4);
  k_cvt<<<512, 256, 0, stream>>>(Whh_b, whh + 786432, 786432 / 4);
  k_cvt<<<2048, 256, 0, stream>>>(fc_w, fcw, 11534336 / 4);
  k_cvt_wc<<<2048, 256, 0, stream>>>(conv_w2, conv_w3, conv_w4, wc_);
  k_prep<<<12, 256, 0, stream>>>(bih_f, bih_b, fc_b, bn_gamma, bn_beta, bn_mean, bn_var, bih, bns, bnt);

  // xg = videos @ [Wih_f;Wih_b]^T + bih  (f32 out)
  gemm_bt<<<dim3(24, 64), 256, 0, stream>>>(vid, wih, xg, nullptr, 8192, 3072, 2048, 64, nullptr, bih);

  {
    const float* xg_c = xg; const u16* whh_c = whh;
    u16* hb_c = hb; float* hs_c = hs; int* flg_c = flg;
    const float* bf_c = bhh_f; const float* bb_c = bhh_b;
    void* args[] = { (void*)&xg_c, (void*)&whh_c, (void*)&bf_c, (void*)&bb_c,
                     (void*)&hb_c, (void*)&hs_c, (void*)&flg_c };
    hipLaunchCooperativeKernel(reinterpret_cast<void*>(gru_rec), dim3(128), dim3(512), args, 0, stream);
  }

  k_mask_pool<<<128, 256, 0, stream>>>(hs, lengths, videos_origin, motions, maskb, feat);
  // z = masked @ Wc^T  (9 shifted conv col-blocks), bf16 out
  gemm_bt<<<dim3(36, 64), 256, 0, stream>>>(maskb, wc_, nullptr, zb16, 8192, 4608, 1024, 32, nullptr, nullptr);
  k_conv_finish<<<dim3(128, 3), 512, 0, stream>>>(zb16, conv_b2, conv_b3, conv_b4, feat);
  // FC split-K x4 (raw partials; BN folded into l2norm)
  gemm_bt<<<dim3(16, 1, 4), 256, 0, stream>>>(feat, fcw, fcp, nullptr, 128, 2048, 5632, 44, nullptr, nullptr);
  k_l2norm<<<128, 256, 0, stream>>>(fcp, bns, bnt, out);
}